// Round 1
// baseline (301.280 us; speedup 1.0000x reference)
//
#include <hip/hip_runtime.h>

typedef unsigned short ushort_t;
typedef __bf16 bf16_t;
typedef __attribute__((ext_vector_type(8))) __bf16 bf16x8;
typedef __attribute__((ext_vector_type(4))) float floatx4;

#define BM 128
#define BN 128
#define BK 32

__device__ __forceinline__ ushort_t f2bf(float f) {
    unsigned int u = __builtin_bit_cast(unsigned int, f);
    u = (u + 0x7fffu + ((u >> 16) & 1u)) >> 16;
    return (ushort_t)u;
}

__device__ __forceinline__ void async16(const ushort_t* g, ushort_t* l) {
    __builtin_amdgcn_global_load_lds(
        (const __attribute__((address_space(1))) unsigned int*)g,
        (__attribute__((address_space(3))) unsigned int*)l,
        16 /*bytes*/, 0 /*offset*/, 0 /*aux*/);
}

// ---------------------------------------------------------------------------
// fp32 -> bf16 conversion for x, W_q, W_k, W_v into one contiguous dst region
// ---------------------------------------------------------------------------
__global__ void cvt_kernel(const float* __restrict__ x,
                           const float* __restrict__ wq,
                           const float* __restrict__ wk,
                           const float* __restrict__ wv,
                           ushort_t* __restrict__ dst) {
    const long NX = 8388608, NW = 1048576;
    long g = ((long)blockIdx.x * blockDim.x + threadIdx.x) * 4;
    const float* src;
    long off;
    if (g < NX)            { src = x;  off = g; }
    else if (g < NX + NW)  { src = wq; off = g - NX; }
    else if (g < NX + 2*NW){ src = wk; off = g - NX - NW; }
    else                   { src = wv; off = g - NX - 2*NW; }
    float4 v = *(const float4*)(src + off);
    ushort_t o0 = f2bf(v.x), o1 = f2bf(v.y), o2 = f2bf(v.z), o3 = f2bf(v.w);
    ushort4 o; o.x = o0; o.y = o1; o.z = o2; o.w = o3;
    *(ushort4*)(dst + g) = o;
}

// ---------------------------------------------------------------------------
// m97-pattern bf16 GEMM: C[m][n] = sum_k A[m][k] * B[n][k]   (B is K-contig)
// EPI 0: store bf16(acc)
// EPI 1: store bf16(exp(acc*scale))          (unnormalized softmax numerator)
// EPI 2: store fp32(acc * linv[z*2048+row])  (normalized attention output)
// ---------------------------------------------------------------------------
template <int EPI, typename OutT>
__global__ __launch_bounds__(256) void gemm_bt(
    const ushort_t* __restrict__ A, long long sA, int lda,
    const ushort_t* __restrict__ B, long long sB, int ldb,
    OutT* __restrict__ C, long long sC, int ldc,
    int K, float scale, const float* __restrict__ linv) {

    A += (long long)blockIdx.z * sA;
    B += (long long)blockIdx.z * sB;
    C += (long long)blockIdx.z * sC;

    __shared__ __align__(16) ushort_t As[BM * BK];
    __shared__ __align__(16) ushort_t Bs[BN * BK];

    const int tid  = threadIdx.x;
    const int lane = tid & 63;
    const int wave = tid >> 6;
    const int wm   = wave >> 1, wn = wave & 1;
    const int quad = lane >> 4;
    const int l16  = lane & 15;

    const int tile_m = blockIdx.y * BM;
    const int tile_n = blockIdx.x * BN;

    floatx4 acc[4][4];
#pragma unroll
    for (int i = 0; i < 4; i++)
#pragma unroll
        for (int j = 0; j < 4; j++) acc[i][j] = (floatx4){0.f, 0.f, 0.f, 0.f};

    const int s0 = tid;        // segment 0..255
    const int s1 = tid + 256;  // segment 256..511  (512 segs of 16B per tile)

    for (int k0 = 0; k0 < K; k0 += BK) {
        __syncthreads();
        // stage A tile [BM][BK] and B tile [BN][BK], 16B per lane per instr
        {
            const ushort_t* ga0 = A + (long)((s0 >> 2) + tile_m) * lda + k0 + (s0 & 3) * 8;
            const ushort_t* ga1 = A + (long)((s1 >> 2) + tile_m) * lda + k0 + (s1 & 3) * 8;
            async16(ga0, &As[s0 * 8]);
            async16(ga1, &As[s1 * 8]);
            const ushort_t* gb0 = B + (long)((s0 >> 2) + tile_n) * ldb + k0 + (s0 & 3) * 8;
            const ushort_t* gb1 = B + (long)((s1 >> 2) + tile_n) * ldb + k0 + (s1 & 3) * 8;
            async16(gb0, &Bs[s0 * 8]);
            async16(gb1, &Bs[s1 * 8]);
        }
        __syncthreads();

        bf16x8 af[4], bfr[4];
#pragma unroll
        for (int im = 0; im < 4; im++) {
            int r = wm * 64 + im * 16 + l16;
            af[im] = *(const bf16x8*)&As[r * BK + quad * 8];
        }
#pragma unroll
        for (int in = 0; in < 4; in++) {
            int c = wn * 64 + in * 16 + l16;
            bfr[in] = *(const bf16x8*)&Bs[c * BK + quad * 8];
        }
#pragma unroll
        for (int im = 0; im < 4; im++)
#pragma unroll
            for (int in = 0; in < 4; in++)
                acc[im][in] = __builtin_amdgcn_mfma_f32_16x16x32_bf16(
                    af[im], bfr[in], acc[im][in], 0, 0, 0);
    }

    // epilogue: lane holds C[row = im*16 + quad*4 + r][col = in*16 + l16]
#pragma unroll
    for (int im = 0; im < 4; im++) {
#pragma unroll
        for (int r = 0; r < 4; r++) {
            int row = tile_m + wm * 64 + im * 16 + quad * 4 + r;
            float li = 1.0f;
            if constexpr (EPI == 2) li = linv[(long)blockIdx.z * 2048 + row];
#pragma unroll
            for (int in = 0; in < 4; in++) {
                int col = tile_n + wn * 64 + in * 16 + l16;
                float v = acc[im][in][r];
                if constexpr (EPI == 0) {
                    ((ushort_t*)C)[(long)row * ldc + col] = f2bf(v);
                } else if constexpr (EPI == 1) {
                    ((ushort_t*)C)[(long)row * ldc + col] = f2bf(__expf(v * scale));
                } else {
                    ((float*)C)[(long)row * ldc + col] = v * li;
                }
            }
        }
    }
}

// ---------------------------------------------------------------------------
// per-row sum of exp-scores -> reciprocal (for softmax normalization)
// P: [8192 rows][2048 cols] bf16 ;  linv[row] = 1/sum(row)
// ---------------------------------------------------------------------------
__global__ void rowsum_kernel(const ushort_t* __restrict__ P, float* __restrict__ linv) {
    int row = blockIdx.x;
    const uint4* p = (const uint4*)(P + (long)row * 2048);
    uint4 v = p[threadIdx.x];  // 8 bf16 per thread
    float s = 0.f;
    unsigned int a[4] = {v.x, v.y, v.z, v.w};
#pragma unroll
    for (int i = 0; i < 4; i++) {
        s += __builtin_bit_cast(float, a[i] << 16);
        s += __builtin_bit_cast(float, a[i] & 0xffff0000u);
    }
#pragma unroll
    for (int off = 32; off; off >>= 1) s += __shfl_down(s, off, 64);
    __shared__ float red[4];
    int wv = threadIdx.x >> 6, lane = threadIdx.x & 63;
    if (lane == 0) red[wv] = s;
    __syncthreads();
    if (threadIdx.x == 0) linv[row] = 1.0f / (red[0] + red[1] + red[2] + red[3]);
}

// ---------------------------------------------------------------------------
extern "C" void kernel_launch(void* const* d_in, const int* in_sizes, int n_in,
                              void* d_out, int out_size, void* d_ws, size_t ws_size,
                              hipStream_t stream) {
    const float* x  = (const float*)d_in[0];
    const float* wq = (const float*)d_in[1];
    const float* wk = (const float*)d_in[2];
    const float* wv = (const float*)d_in[3];

    // workspace layout (bf16 elements unless noted)
    ushort_t* xb  = (ushort_t*)d_ws;       // 8388608   x as bf16        [8192,1024]
    ushort_t* wqb = xb  + 8388608;         // 1048576   W_q bf16         [1024,1024]
    ushort_t* wkb = wqb + 1048576;         // 1048576   W_k bf16
    ushort_t* wvb = wkb + 1048576;         // 1048576   W_v bf16
    ushort_t* Qb  = wvb + 1048576;         // 8388608   Q bf16           [8192,1024]
    ushort_t* Kb  = Qb  + 8388608;         // 8388608   K bf16           [8192,1024]
    ushort_t* VTb = Kb  + 8388608;         // 8388608   V^T bf16         [1024,8192]
    ushort_t* Pb  = VTb + 8388608;         // 16777216  exp-scores bf16  [4][2048][2048]
    float*    linv = (float*)(Pb + 16777216); // 8192 fp32
    float*    out  = (float*)d_out;

    const float scale = 0.022097086912079608f;  // 1/sqrt(2048)

    // 1) fp32 -> bf16 for x, Wq, Wk, Wv
    cvt_kernel<<<11264, 256, 0, stream>>>(x, wq, wk, wv, xb);

    // 2) Q = x Wq^T, K = x Wk^T   (M=8192, N=1024, K=1024; z picks Wq/Wk)
    gemm_bt<0, ushort_t><<<dim3(8, 64, 2), 256, 0, stream>>>(
        xb, 0, 1024, wqb, 1048576, 1024, Qb, 8388608, 1024, 1024, 0.f, nullptr);

    // 3) V^T = Wv x^T             (M=1024, N=8192, K=1024)
    gemm_bt<0, ushort_t><<<dim3(64, 8, 1), 256, 0, stream>>>(
        wvb, 0, 1024, xb, 0, 1024, VTb, 0, 8192, 1024, 0.f, nullptr);

    // 4) P = exp(scale * Q K^T) per batch (M=N=2048, K=1024; z = batch)
    gemm_bt<1, ushort_t><<<dim3(16, 16, 4), 256, 0, stream>>>(
        Qb, 2097152, 1024, Kb, 2097152, 1024, Pb, 4194304, 2048, 1024, scale, nullptr);

    // 5) linv[row] = 1 / sum_k P[row][k]
    rowsum_kernel<<<8192, 256, 0, stream>>>(Pb, linv);

    // 6) out = (P V) * linv per batch (M=2048, N=1024, K=2048; B = V^T slice)
    gemm_bt<2, float><<<dim3(8, 16, 4), 256, 0, stream>>>(
        Pb, 4194304, 2048, VTb, 2048, 8192, out, 2097152, 1024, 2048, 0.f, linv);
}

// Round 2
// 277.139 us; speedup vs baseline: 1.0871x; 1.0871x over previous
//
#include <hip/hip_runtime.h>

typedef unsigned short ushort_t;
typedef __attribute__((ext_vector_type(8))) __bf16 bf16x8;
typedef __attribute__((ext_vector_type(4))) float floatx4;

__device__ __forceinline__ ushort_t f2bf(float f) {
    unsigned int u = __builtin_bit_cast(unsigned int, f);
    u = (u + 0x7fffu + ((u >> 16) & 1u)) >> 16;
    return (ushort_t)u;
}

__device__ __forceinline__ void async16(const ushort_t* g, ushort_t* l) {
    __builtin_amdgcn_global_load_lds(
        (const __attribute__((address_space(1))) unsigned int*)g,
        (__attribute__((address_space(3))) unsigned int*)l,
        16 /*bytes*/, 0 /*offset*/, 0 /*aux*/);
}

// XOR-swizzled LDS offset (ushort index) of the 8-element group (row, cg).
// Breaks the 8-lanes-per-4-bank pattern of the unswizzled layout; read pattern
// becomes 2 lanes/bank-group which is free (m136).
__device__ __forceinline__ int sw(int row, int cg) {
    return ((row << 2) + ((cg ^ row ^ (row >> 2)) & 3)) << 3;
}

// ---------------------------------------------------------------------------
// Core bf16 GEMM tile: acc[m][n] += sum_k A[m][k] * B[n][k]  (both K-contig)
// BM_ x BN_ tile, 4 waves in 2x2 grid, IM_ x IN_ mfma(16x16x32) per wave.
// ---------------------------------------------------------------------------
template <int BM_, int BN_, int IM_, int IN_>
__device__ __forceinline__ void gemm_core(
    const ushort_t* __restrict__ A, int lda,
    const ushort_t* __restrict__ B, int ldb,
    int K, int tile_m, int tile_n,
    ushort_t* As, ushort_t* Bs,
    floatx4 (&acc)[IM_][IN_]) {

    const int tid  = threadIdx.x;
    const int lane = tid & 63;
    const int wave = tid >> 6;
    const int wm   = wave >> 1, wn = wave & 1;
    const int quad = lane >> 4;
    const int l16  = lane & 15;

#pragma unroll
    for (int i = 0; i < IM_; i++)
#pragma unroll
        for (int j = 0; j < IN_; j++) acc[i][j] = (floatx4){0.f, 0.f, 0.f, 0.f};

    for (int k0 = 0; k0 < K; k0 += 32) {
        __syncthreads();
#pragma unroll
        for (int i = 0; i < BM_ * 4 / 256; i++) {
            int s = tid + i * 256;
            int row = s >> 2, cg = (s ^ row ^ (row >> 2)) & 3;
            async16(A + (long)(row + tile_m) * lda + k0 + cg * 8, &As[s * 8]);
        }
#pragma unroll
        for (int i = 0; i < BN_ * 4 / 256; i++) {
            int s = tid + i * 256;
            int row = s >> 2, cg = (s ^ row ^ (row >> 2)) & 3;
            async16(B + (long)(row + tile_n) * ldb + k0 + cg * 8, &Bs[s * 8]);
        }
        __syncthreads();

        bf16x8 af[IM_], bfr[IN_];
#pragma unroll
        for (int im = 0; im < IM_; im++)
            af[im] = *(const bf16x8*)&As[sw(wm * IM_ * 16 + im * 16 + l16, quad)];
#pragma unroll
        for (int in = 0; in < IN_; in++)
            bfr[in] = *(const bf16x8*)&Bs[sw(wn * IN_ * 16 + in * 16 + l16, quad)];
#pragma unroll
        for (int im = 0; im < IM_; im++)
#pragma unroll
            for (int in = 0; in < IN_; in++)
                acc[im][in] = __builtin_amdgcn_mfma_f32_16x16x32_bf16(
                    af[im], bfr[in], acc[im][in], 0, 0, 0);
    }
}

// ---------------------------------------------------------------------------
// fp32 -> bf16 conversion for x, W_q, W_k, W_v ; trailing blocks zero lsum
// ---------------------------------------------------------------------------
__global__ void cvt_kernel(const float* __restrict__ x,
                           const float* __restrict__ wq,
                           const float* __restrict__ wk,
                           const float* __restrict__ wv,
                           ushort_t* __restrict__ dst,
                           float* __restrict__ lsum) {
    if (blockIdx.x >= 11264) {
        int idx = (blockIdx.x - 11264) * 256 + threadIdx.x;  // [0,2048)
        ((float4*)lsum)[idx] = (float4){0.f, 0.f, 0.f, 0.f};
        return;
    }
    const long NX = 8388608, NW = 1048576;
    long g = ((long)blockIdx.x * blockDim.x + threadIdx.x) * 4;
    const float* src;
    long off;
    if (g < NX)             { src = x;  off = g; }
    else if (g < NX + NW)   { src = wq; off = g - NX; }
    else if (g < NX + 2*NW) { src = wk; off = g - NX - NW; }
    else                    { src = wv; off = g - NX - 2*NW; }
    float4 v = *(const float4*)(src + off);
    ushort4 o;
    o.x = f2bf(v.x); o.y = f2bf(v.y); o.z = f2bf(v.z); o.w = f2bf(v.w);
    *(ushort4*)(dst + g) = o;
}

// ---------------------------------------------------------------------------
// Fused projections: z=0 -> Q = x Wq^T, z=1 -> K = x Wk^T, z=2 -> V^T = Wv x^T
// ---------------------------------------------------------------------------
__global__ __launch_bounds__(256) void qkv_kernel(
    const ushort_t* __restrict__ xb,
    const ushort_t* __restrict__ wqb,
    const ushort_t* __restrict__ wkb,
    const ushort_t* __restrict__ wvb,
    ushort_t* __restrict__ Qb,
    ushort_t* __restrict__ Kb,
    ushort_t* __restrict__ VTb) {

    __shared__ __align__(16) ushort_t As[128 * 32];
    __shared__ __align__(16) ushort_t Bs[128 * 32];

    const int z = blockIdx.z;
    const ushort_t *A, *B;
    ushort_t* C;
    int ldc, tile_m, tile_n;
    if (z == 2) {  // V^T = Wv x^T : M=1024 (8 tiles, x), N=8192 (64 tiles, y)
        A = wvb; B = xb; C = VTb; ldc = 8192;
        tile_m = blockIdx.x * 128; tile_n = blockIdx.y * 128;
    } else {       // Q/K = x W^T : M=8192 (64 tiles, y), N=1024 (8 tiles, x)
        A = xb; B = z ? wkb : wqb; C = z ? Kb : Qb; ldc = 1024;
        tile_m = blockIdx.y * 128; tile_n = blockIdx.x * 128;
    }

    floatx4 acc[4][4];
    gemm_core<128, 128, 4, 4>(A, 1024, B, 1024, 1024, tile_m, tile_n, As, Bs, acc);

    const int lane = threadIdx.x & 63, wave = threadIdx.x >> 6;
    const int wm = wave >> 1, wn = wave & 1, quad = lane >> 4, l16 = lane & 15;
#pragma unroll
    for (int im = 0; im < 4; im++)
#pragma unroll
        for (int r = 0; r < 4; r++) {
            int row = tile_m + wm * 64 + im * 16 + quad * 4 + r;
#pragma unroll
            for (int in = 0; in < 4; in++) {
                int col = tile_n + wn * 64 + in * 16 + l16;
                C[(long)row * ldc + col] = f2bf(acc[im][in][r]);
            }
        }
}

// ---------------------------------------------------------------------------
// P = exp(scale * Q K^T) per batch + fused row-sum atomics into lsum
// ---------------------------------------------------------------------------
__global__ __launch_bounds__(256) void pexp_kernel(
    const ushort_t* __restrict__ Qb,
    const ushort_t* __restrict__ Kb,
    ushort_t* __restrict__ Pb,
    float* __restrict__ lsum) {

    __shared__ __align__(16) ushort_t As[128 * 32];
    __shared__ __align__(16) ushort_t Bs[128 * 32];

    const int z = blockIdx.z;
    const ushort_t* A = Qb + (long)z * 2097152;
    const ushort_t* B = Kb + (long)z * 2097152;
    ushort_t* C = Pb + (long)z * 4194304;
    float* l = lsum + z * 2048;
    const int tile_m = blockIdx.y * 128;
    const int tile_n = blockIdx.x * 128;

    floatx4 acc[4][4];
    gemm_core<128, 128, 4, 4>(A, 1024, B, 1024, 1024, tile_m, tile_n, As, Bs, acc);

    const float scale = 0.022097086912079608f;  // 1/sqrt(2048)
    const int lane = threadIdx.x & 63, wave = threadIdx.x >> 6;
    const int wm = wave >> 1, wn = wave & 1, quad = lane >> 4, l16 = lane & 15;
#pragma unroll
    for (int im = 0; im < 4; im++)
#pragma unroll
        for (int r = 0; r < 4; r++) {
            int row = tile_m + wm * 64 + im * 16 + quad * 4 + r;
            float psum = 0.f;
#pragma unroll
            for (int in = 0; in < 4; in++) {
                int col = tile_n + wn * 64 + in * 16 + l16;
                float e = __expf(acc[im][in][r] * scale);
                C[(long)row * 2048 + col] = f2bf(e);
                psum += e;
            }
            // reduce across the 16 l16 lanes (same quad), then one atomic
            psum += __shfl_xor(psum, 1, 64);
            psum += __shfl_xor(psum, 2, 64);
            psum += __shfl_xor(psum, 4, 64);
            psum += __shfl_xor(psum, 8, 64);
            if (l16 == 0) atomicAdd(&l[row], psum);
        }
}

// ---------------------------------------------------------------------------
// out = (P V) / l per batch ; BN=64 tile for 2x residency (latency-bound)
// ---------------------------------------------------------------------------
__global__ __launch_bounds__(256) void out_kernel(
    const ushort_t* __restrict__ Pb,
    const ushort_t* __restrict__ VTb,
    float* __restrict__ out,
    const float* __restrict__ lsum) {

    __shared__ __align__(16) ushort_t As[128 * 32];
    __shared__ __align__(16) ushort_t Bs[64 * 32];

    const int z = blockIdx.z;
    const ushort_t* A = Pb + (long)z * 4194304;   // [2048][2048]
    const ushort_t* B = VTb + (long)z * 2048;     // rows: ldb=8192, batch col slice
    float* C = out + (long)z * 2097152;
    const float* l = lsum + z * 2048;
    const int tile_m = blockIdx.y * 128;
    const int tile_n = blockIdx.x * 64;

    floatx4 acc[4][2];
    gemm_core<128, 64, 4, 2>(A, 2048, B, 8192, 2048, tile_m, tile_n, As, Bs, acc);

    const int lane = threadIdx.x & 63, wave = threadIdx.x >> 6;
    const int wm = wave >> 1, wn = wave & 1, quad = lane >> 4, l16 = lane & 15;
#pragma unroll
    for (int im = 0; im < 4; im++)
#pragma unroll
        for (int r = 0; r < 4; r++) {
            int row = tile_m + wm * 64 + im * 16 + quad * 4 + r;
            float li = 1.0f / l[row];
#pragma unroll
            for (int in = 0; in < 2; in++) {
                int col = tile_n + wn * 32 + in * 16 + l16;
                C[(long)row * 1024 + col] = acc[im][in][r] * li;
            }
        }
}

// ---------------------------------------------------------------------------
extern "C" void kernel_launch(void* const* d_in, const int* in_sizes, int n_in,
                              void* d_out, int out_size, void* d_ws, size_t ws_size,
                              hipStream_t stream) {
    const float* x  = (const float*)d_in[0];
    const float* wq = (const float*)d_in[1];
    const float* wk = (const float*)d_in[2];
    const float* wv = (const float*)d_in[3];

    ushort_t* xb  = (ushort_t*)d_ws;          // [8192,1024] bf16
    ushort_t* wqb = xb  + 8388608;            // [1024,1024]
    ushort_t* wkb = wqb + 1048576;
    ushort_t* wvb = wkb + 1048576;
    ushort_t* Qb  = wvb + 1048576;            // [8192,1024]
    ushort_t* Kb  = Qb  + 8388608;            // [8192,1024]
    ushort_t* VTb = Kb  + 8388608;            // [1024,8192]
    ushort_t* Pb  = VTb + 8388608;            // [4][2048][2048]
    float*    lsum = (float*)(Pb + 16777216); // [4][2048] fp32 row sums
    float*    out  = (float*)d_out;

    // 1) fp32->bf16 (+ zero lsum in trailing 8 blocks)
    cvt_kernel<<<11272, 256, 0, stream>>>(x, wq, wk, wv, xb, lsum);

    // 2) Q, K, V^T in one dispatch (1536 blocks)
    qkv_kernel<<<dim3(8, 64, 3), 256, 0, stream>>>(xb, wqb, wkb, wvb, Qb, Kb, VTb);

    // 3) P = exp(scale * Q K^T) + row sums (1024 blocks)
    pexp_kernel<<<dim3(16, 16, 4), 256, 0, stream>>>(Qb, Kb, Pb, lsum);

    // 4) out = (P V) / l (1024 blocks)
    out_kernel<<<dim3(16, 16, 4), 256, 0, stream>>>(Pb, VTb, out, lsum);
}